// Round 4
// baseline (480.223 us; speedup 1.0000x reference)
//
#include <hip/hip_runtime.h>
#include <hip/hip_bf16.h>

#define GG 128   // num_graphs (static in problem)

// ------------- degrees + ranks, 4-replica split (returning atomics) --------
__global__ __launch_bounds__(256) void deg_rank(const int* __restrict__ ei,
                                                int* __restrict__ degfR,
                                                int* __restrict__ degbR,
                                                int* __restrict__ rankf,
                                                int* __restrict__ rankb,
                                                int e, int n) {
    int i = blockIdx.x * 256 + threadIdx.x;
    if (i >= e) return;
    int s = ei[i], d = ei[e + i];
    int r = i & 3;
    rankf[i] = atomicAdd(degfR + (size_t)r * n + d, 1);
    rankb[i] = atomicAdd(degbR + (size_t)r * n + s, 1);
}

// ------------- sum replicas -> full degrees ---------------------------------
__global__ __launch_bounds__(256) void sum_reps(const int* __restrict__ degfR,
                                                const int* __restrict__ degbR,
                                                int* __restrict__ degf,
                                                int* __restrict__ degb, int n) {
    int i = blockIdx.x * 256 + threadIdx.x;
    if (i >= n) return;
    degf[i] = degfR[i] + degfR[n + i] + degfR[2 * (size_t)n + i] + degfR[3 * (size_t)n + i];
    degb[i] = degbR[i] + degbR[n + i] + degbR[2 * (size_t)n + i] + degbR[3 * (size_t)n + i];
}

// ---------------- 3-phase exclusive scan (f and b via blockIdx.y) -----------
__global__ __launch_bounds__(256) void scan1(const int* __restrict__ degf,
                                             const int* __restrict__ degb,
                                             int* __restrict__ part_f,
                                             int* __restrict__ part_b, int n) {
    const int* deg = blockIdx.y ? degb : degf;
    int* partial = blockIdx.y ? part_b : part_f;
    __shared__ int s[256];
    int t = threadIdx.x, i = blockIdx.x * 256 + t;
    s[t] = (i < n) ? deg[i] : 0;
    __syncthreads();
    for (int o = 128; o > 0; o >>= 1) {
        if (t < o) s[t] += s[t + o];
        __syncthreads();
    }
    if (t == 0) partial[blockIdx.x] = s[0];
}

__global__ __launch_bounds__(512) void scan2(int* __restrict__ part_f,
                                             int* __restrict__ part_b, int nb) {
    int* partial = blockIdx.x ? part_b : part_f;
    __shared__ int s[512];
    int t = threadIdx.x;
    int v = (t < nb) ? partial[t] : 0;
    s[t] = v;
    __syncthreads();
    for (int o = 1; o < 512; o <<= 1) {
        int u = (t >= o) ? s[t - o] : 0;
        __syncthreads();
        s[t] += u;
        __syncthreads();
    }
    if (t < nb) partial[t] = s[t] - v;  // exclusive
}

__global__ __launch_bounds__(256) void scan3(const int* __restrict__ degf,
                                             const int* __restrict__ degb,
                                             const int* __restrict__ part_f,
                                             const int* __restrict__ part_b,
                                             int* __restrict__ off_f,
                                             int* __restrict__ off_b,
                                             float* __restrict__ invf,
                                             float* __restrict__ invb,
                                             int n, int e) {
    const int* deg = blockIdx.y ? degb : degf;
    const int* partial = blockIdx.y ? part_b : part_f;
    int* off = blockIdx.y ? off_b : off_f;
    float* inv = blockIdx.y ? invb : invf;
    __shared__ int s[256];
    int t = threadIdx.x, i = blockIdx.x * 256 + t;
    int v = (i < n) ? deg[i] : 0;
    s[t] = v;
    __syncthreads();
    for (int o = 1; o < 256; o <<= 1) {
        int u = (t >= o) ? s[t - o] : 0;
        __syncthreads();
        s[t] += u;
        __syncthreads();
    }
    if (i < n) {
        off[i] = partial[blockIdx.x] + s[t] - v;
        inv[i] = 1.f / fmaxf((float)v, 1.f);
    }
    if (i == n - 1) off[n] = e;
}

// ------------- per-node int4 base = off + replica prefix --------------------
__global__ __launch_bounds__(256) void make_base(const int* __restrict__ degfR,
                                                 const int* __restrict__ degbR,
                                                 const int* __restrict__ off_f,
                                                 const int* __restrict__ off_b,
                                                 int4* __restrict__ baseF,
                                                 int4* __restrict__ baseB, int n) {
    int i = blockIdx.x * 256 + threadIdx.x;
    if (i >= n) return;
    {
        int o = off_f[i];
        int c0 = degfR[i], c1 = degfR[n + i], c2 = degfR[2 * (size_t)n + i];
        baseF[i] = make_int4(o, o + c0, o + c0 + c1, o + c0 + c1 + c2);
    }
    {
        int o = off_b[i];
        int c0 = degbR[i], c1 = degbR[n + i], c2 = degbR[2 * (size_t)n + i];
        baseB[i] = make_int4(o, o + c0, o + c0 + c1, o + c0 + c1 + c2);
    }
}

// ---------------- CSR fill: atomic-free scattered stores --------------------
__global__ __launch_bounds__(256) void fill_csr(const int* __restrict__ ei,
                                                const int4* __restrict__ baseF,
                                                const int4* __restrict__ baseB,
                                                const int* __restrict__ rankf,
                                                const int* __restrict__ rankb,
                                                int* __restrict__ csr_f,
                                                int* __restrict__ csr_b, int e) {
    int i = blockIdx.x * 256 + threadIdx.x;
    if (i >= e) return;
    int s = ei[i], d = ei[e + i];
    int r = i & 3;
    int4 bf = baseF[d];
    int4 bb = baseB[s];
    int basef = (r < 2) ? (r == 0 ? bf.x : bf.y) : (r == 2 ? bf.z : bf.w);
    int baseb = (r < 2) ? (r == 0 ? bb.x : bb.y) : (r == 2 ? bb.z : bb.w);
    csr_f[basef + rankf[i]] = s;
    csr_b[baseb + rankb[i]] = d;
}

// ---------------- fused gather + bidirectional SAGE layer -------------------
// pass0: sIn = mean_f tile (gathered), pass1: sIn = mean_b tile, pass2: own x
// out = relu(0.5*(mean_f@Wlf^T + mean_b@Wlb^T + x@(Wrf+Wrb)^T + blf+blb))
__global__ __launch_bounds__(256) void fused_sage(
    const float* __restrict__ X,
    const int* __restrict__ off_f, const int* __restrict__ csr_f,
    const float* __restrict__ invf,
    const int* __restrict__ off_b, const int* __restrict__ csr_b,
    const float* __restrict__ invb,
    const float* __restrict__ Wlf, const float* __restrict__ blf,
    const float* __restrict__ Wrf,
    const float* __restrict__ Wlb, const float* __restrict__ blb,
    const float* __restrict__ Wrb,
    float* __restrict__ Out, int n)
{
    __shared__ float sIn[64][68];
    __shared__ float sW[64][68];
    const int t = threadIdx.x;
    const int base = blockIdx.x * 64;
    const int jg = t & 15;
    const int ng = t >> 4;

    float acc[4][4];
#pragma unroll
    for (int a = 0; a < 4; a++)
#pragma unroll
        for (int b = 0; b < 4; b++) acc[a][b] = 0.f;

    for (int p = 0; p < 3; p++) {
        // ---- stage weights first (independent of gather latency) ----
#pragma unroll
        for (int i = 0; i < 4; i++) {
            int f4 = t + 256 * i;
            int row = f4 >> 4, c4 = f4 & 15;
            float4 w;
            if (p == 0) w = *reinterpret_cast<const float4*>(Wlf + row * 64 + c4 * 4);
            else if (p == 1) w = *reinterpret_cast<const float4*>(Wlb + row * 64 + c4 * 4);
            else {
                float4 w1 = *reinterpret_cast<const float4*>(Wrf + row * 64 + c4 * 4);
                float4 w2 = *reinterpret_cast<const float4*>(Wrb + row * 64 + c4 * 4);
                w = make_float4(w1.x + w2.x, w1.y + w2.y, w1.z + w2.z, w1.w + w2.w);
            }
            *reinterpret_cast<float4*>(&sW[row][c4 * 4]) = w;
        }
        // ---- stage input tile: gathered mean (p<2) or own rows (p==2) ----
        if (p < 2) {
            const int* off = p ? off_b : off_f;
            const int* csr = p ? csr_b : csr_f;
            const float* inv = p ? invb : invf;
#pragma unroll
            for (int i = 0; i < 4; i++) {
                int f4 = t + 256 * i;
                int row = f4 >> 4, c4 = f4 & 15;
                int node = base + row;
                int c = c4 * 4;
                float4 acc4 = make_float4(0.f, 0.f, 0.f, 0.f);
                if (node < n) {
                    int kb = off[node], ke = off[node + 1];
                    int k = kb;
                    for (; k + 3 < ke; k += 4) {
                        int n0 = csr[k], n1 = csr[k + 1], n2 = csr[k + 2], n3 = csr[k + 3];
                        float4 v0 = *reinterpret_cast<const float4*>(X + (size_t)n0 * 64 + c);
                        float4 v1 = *reinterpret_cast<const float4*>(X + (size_t)n1 * 64 + c);
                        float4 v2 = *reinterpret_cast<const float4*>(X + (size_t)n2 * 64 + c);
                        float4 v3 = *reinterpret_cast<const float4*>(X + (size_t)n3 * 64 + c);
                        acc4.x += v0.x + v1.x + v2.x + v3.x;
                        acc4.y += v0.y + v1.y + v2.y + v3.y;
                        acc4.z += v0.z + v1.z + v2.z + v3.z;
                        acc4.w += v0.w + v1.w + v2.w + v3.w;
                    }
                    for (; k < ke; k++) {
                        int s = csr[k];
                        float4 v = *reinterpret_cast<const float4*>(X + (size_t)s * 64 + c);
                        acc4.x += v.x; acc4.y += v.y; acc4.z += v.z; acc4.w += v.w;
                    }
                    float iv = inv[node];
                    acc4.x *= iv; acc4.y *= iv; acc4.z *= iv; acc4.w *= iv;
                }
                *reinterpret_cast<float4*>(&sIn[row][c4 * 4]) = acc4;
            }
        } else {
#pragma unroll
            for (int i = 0; i < 4; i++) {
                int f4 = t + 256 * i;
                int row = f4 >> 4, c4 = f4 & 15;
                int node = base + row;
                float4 v = make_float4(0.f, 0.f, 0.f, 0.f);
                if (node < n)
                    v = *reinterpret_cast<const float4*>(X + (size_t)node * 64 + c4 * 4);
                *reinterpret_cast<float4*>(&sIn[row][c4 * 4]) = v;
            }
        }
        __syncthreads();
        // ---- GEMM pass ----
        for (int kc = 0; kc < 16; kc++) {
            float4 av[4], wv[4];
#pragma unroll
            for (int i = 0; i < 4; i++)
                av[i] = *reinterpret_cast<const float4*>(&sIn[ng + 16 * i][kc * 4]);
#pragma unroll
            for (int i = 0; i < 4; i++)
                wv[i] = *reinterpret_cast<const float4*>(&sW[jg + 16 * i][kc * 4]);
#pragma unroll
            for (int a = 0; a < 4; a++)
#pragma unroll
                for (int b = 0; b < 4; b++)
                    acc[a][b] += av[a].x * wv[b].x + av[a].y * wv[b].y +
                                 av[a].z * wv[b].z + av[a].w * wv[b].w;
        }
        __syncthreads();
    }
#pragma unroll
    for (int b = 0; b < 4; b++) {
        int j = jg + 16 * b;
        float bias = 0.5f * (blf[j] + blb[j]);
#pragma unroll
        for (int a = 0; a < 4; a++) {
            int grow = base + ng + 16 * a;
            if (grow < n) {
                float v = 0.5f * acc[a][b] + bias;
                Out[(size_t)grow * 64 + j] = v > 0.f ? v : 0.f;
            }
        }
    }
}

// ---------------- pooling: per-block LDS [G][64] accumulator ----------------
__global__ __launch_bounds__(256) void pool_partial(const float* __restrict__ H,
                                                    const int* __restrict__ batch,
                                                    float* __restrict__ psum,
                                                    float* __restrict__ pcnt, int n) {
    __shared__ float ls[GG * 64];
    __shared__ float lc[GG];
    int t = threadIdx.x;
    for (int i = t; i < GG * 64; i += 256) ls[i] = 0.f;
    for (int i = t; i < GG; i += 256) lc[i] = 0.f;
    __syncthreads();
    int chunk = (n + gridDim.x - 1) / gridDim.x;
    int base = blockIdx.x * chunk;
    int end = base + chunk; if (end > n) end = n;
    int f = t & 63, r = t >> 6;
    for (int node = base + r; node < end; node += 4) {
        int g = batch[node];
        float v = H[(size_t)node * 64 + f];
        atomicAdd(&ls[g * 64 + f], v);
        if (f == 0) atomicAdd(&lc[g], 1.f);
    }
    __syncthreads();
    for (int i = t; i < GG * 64; i += 256) {
        float v = ls[i];
        if (v != 0.f) atomicAdd(&psum[i], v);
    }
    for (int i = t; i < GG; i += 256) {
        float v = lc[i];
        if (v != 0.f) atomicAdd(&pcnt[i], v);
    }
}

// ---------------- head ----------------
__global__ __launch_bounds__(256) void pool_final(const float* __restrict__ psum,
                                                  const float* __restrict__ pcnt,
                                                  const float* __restrict__ PW,
                                                  const float* __restrict__ Pb,
                                                  float* __restrict__ out) {
    int t = blockIdx.x * 256 + threadIdx.x;
    int g = t >> 4, o = t & 15;
    if (g >= GG) return;
    float inv = 1.f / fmaxf(pcnt[g], 1.f);
    float acc = 0.f;
#pragma unroll 8
    for (int k = 0; k < 64; k++) acc += psum[g * 64 + k] * PW[o * 64 + k];
    out[t] = acc * inv + Pb[o];
}

extern "C" void kernel_launch(void* const* d_in, const int* in_sizes, int n_in,
                              void* d_out, int out_size, void* d_ws, size_t ws_size,
                              hipStream_t stream) {
    const float* x      = (const float*)d_in[0];
    const int*   ei     = (const int*)d_in[1];
    const int*   batch  = (const int*)d_in[2];
    const float* l0f_Wl = (const float*)d_in[4];
    const float* l0f_bl = (const float*)d_in[5];
    const float* l0f_Wr = (const float*)d_in[6];
    const float* l0b_Wl = (const float*)d_in[7];
    const float* l0b_bl = (const float*)d_in[8];
    const float* l0b_Wr = (const float*)d_in[9];
    const float* l1f_Wl = (const float*)d_in[10];
    const float* l1f_bl = (const float*)d_in[11];
    const float* l1f_Wr = (const float*)d_in[12];
    const float* l1b_Wl = (const float*)d_in[13];
    const float* l1b_bl = (const float*)d_in[14];
    const float* l1b_Wr = (const float*)d_in[15];
    const float* pred_W = (const float*)d_in[16];
    const float* pred_b = (const float*)d_in[17];

    const int n = in_sizes[0] / 64;
    const int e = in_sizes[1] / 2;
    const size_t N64 = (size_t)n * 64;
    const int nb = (n + 255) / 256;

    // ---- workspace layout (element offsets, 16B-aligned where needed) ----
    int* ws = (int*)d_ws;
    size_t o = 0;
    int*   degfR = ws + o;  o += 4 * (size_t)n;          // zeroed
    int*   degbR = ws + o;  o += 4 * (size_t)n;          // zeroed
    float* psum  = (float*)(ws + o); o += GG * 64;       // zeroed
    float* pcnt  = (float*)(ws + o); o += GG;            // zeroed
    size_t zcount = o;
    int*   degf  = ws + o;  o += n;
    int*   degb  = ws + o;  o += n;
    int*   off_f = ws + o;  o += n + 1;
    int*   off_b = ws + o;  o += n + 1;
    o = (o + 3) & ~(size_t)3;
    int4*  baseF = (int4*)(ws + o); o += 4 * (size_t)n;
    int4*  baseB = (int4*)(ws + o); o += 4 * (size_t)n;
    int*   rankf = ws + o;  o += e;
    int*   rankb = ws + o;  o += e;
    int*   csr_f = ws + o;  o += e;
    int*   csr_b = ws + o;  o += e;
    int*   part_f = ws + o; o += 512;
    int*   part_b = ws + o; o += 512;
    float* invf  = (float*)(ws + o); o += n;
    float* invb  = (float*)(ws + o); o += n;
    o = (o + 3) & ~(size_t)3;
    float* h0    = (float*)(ws + o); o += N64;
    float* h1    = (float*)(ws + o); o += N64;

    hipMemsetAsync(ws, 0, zcount * sizeof(int), stream);

    // CSR build (once; reused by both layers)
    deg_rank<<<(e + 255) / 256, 256, 0, stream>>>(ei, degfR, degbR, rankf, rankb, e, n);
    sum_reps<<<nb, 256, 0, stream>>>(degfR, degbR, degf, degb, n);
    scan1<<<dim3(nb, 2), 256, 0, stream>>>(degf, degb, part_f, part_b, n);
    scan2<<<2, 512, 0, stream>>>(part_f, part_b, nb);
    scan3<<<dim3(nb, 2), 256, 0, stream>>>(degf, degb, part_f, part_b,
                                           off_f, off_b, invf, invb, n, e);
    make_base<<<nb, 256, 0, stream>>>(degfR, degbR, off_f, off_b, baseF, baseB, n);
    fill_csr<<<(e + 255) / 256, 256, 0, stream>>>(ei, baseF, baseB, rankf, rankb,
                                                  csr_f, csr_b, e);

    // layer 0 (gather fused into GEMM)
    fused_sage<<<(n + 63) / 64, 256, 0, stream>>>(x,
        off_f, csr_f, invf, off_b, csr_b, invb,
        l0f_Wl, l0f_bl, l0f_Wr, l0b_Wl, l0b_bl, l0b_Wr, h0, n);

    // layer 1
    fused_sage<<<(n + 63) / 64, 256, 0, stream>>>(h0,
        off_f, csr_f, invf, off_b, csr_b, invb,
        l1f_Wl, l1f_bl, l1f_Wr, l1b_Wl, l1b_bl, l1b_Wr, h1, n);

    // pooling + head
    pool_partial<<<256, 256, 0, stream>>>(h1, batch, psum, pcnt, n);
    pool_final<<<8, 256, 0, stream>>>(psum, pcnt, pred_W, pred_b, (float*)d_out);
}